// Round 1
// baseline (326.659 us; speedup 1.0000x reference)
//
#include <hip/hip_runtime.h>

#define BSZN 8
#define TT 4096
#define DIN 512
#define PP 256
#define HHH 256
#define DOUT 512
#define LCH 32              // scan chunk length == row tile
#define NCH (TT / LCH)      // 128 chunks per batch
#define NBLK (BSZN * NCH)   // 1024 blocks -> 4 blocks/CU co-resident
#define XPS 264             // padded LDS row stride (bf16) for xp/hsL
#define XTS 520             // padded LDS row stride (bf16) for x tile

typedef __attribute__((ext_vector_type(8))) short bf16x8;
typedef __attribute__((ext_vector_type(4))) float f32x4;

static __device__ __forceinline__ unsigned short f2bf(float x) {
  union { float f; unsigned u; } t{x};
  unsigned r = t.u + 0x7fffu + ((t.u >> 16) & 1u);  // RNE
  return (unsigned short)(r >> 16);
}

static __device__ __forceinline__ float ld_carry(const float* p) {
  return __hip_atomic_load(p, __ATOMIC_RELAXED, __HIP_MEMORY_SCOPE_AGENT);
}

// ---------------------------------------------------------------------------
// Prep: Wi->bf16 (128 blk), B->B^T bf16 (16 tile blks, coalesced writes),
// zero flags (1 blk), CWT = Wo @ C^T via 32 blocks of 64x64 tiles.
// Grid = 128 + 16 + 1 + 32 = 177.
// ---------------------------------------------------------------------------
__global__ __launch_bounds__(256) void prep_k(
    const float* __restrict__ Wi, const float* __restrict__ Wo,
    const float* __restrict__ Cm, const float* __restrict__ Bm,
    unsigned short* __restrict__ Wi_b, unsigned short* __restrict__ B_bT,
    unsigned short* __restrict__ CWT_b, int* __restrict__ flag_g) {
  __shared__ alignas(16) char smem[8192];
  const int b = blockIdx.x, tid = threadIdx.x;
  if (b < 128) {                       // Wi convert (256x512 f32 -> bf16)
    const int idx = b * 1024 + tid * 4;
    const float4 v = *(const float4*)(Wi + idx);
    uint2 w;
    w.x = (unsigned)f2bf(v.x) | ((unsigned)f2bf(v.y) << 16);
    w.y = (unsigned)f2bf(v.z) | ((unsigned)f2bf(v.w) << 16);
    *(uint2*)(Wi_b + idx) = w;
  } else if (b < 144) {                // B transpose: 16 tiles of 64x64
    const int t = b - 128;
    const int p0 = (t >> 2) * 64, h0 = (t & 3) * 64;
#pragma unroll 4
    for (int it = 0; it < 16; ++it) {
      const int f = it * 256 + tid;
      const int oh = f >> 6, op = f & 63;   // coalesced bf16 row writes
      B_bT[(size_t)(h0 + oh) * PP + p0 + op] =
          f2bf(Bm[(size_t)(p0 + op) * HHH + h0 + oh]);
    }
  } else if (b == 144) {               // zero lookback flags (ws poisoned!)
    for (int i = tid; i < NBLK; i += 256) flag_g[i] = 0;
  } else {                             // CWT: 32 blocks of 64x64 tiles
    const int t = b - 145;
    const int m0 = (t >> 2) * 64, n0 = (t & 3) * 64;
    char* As = smem;
    char* Bs = smem + 4096;
    const int wave = tid >> 6, lane = tid & 63;
    const int l15 = lane & 15, q = lane >> 4;
    const int wrow = (wave >> 1) * 32, wcol = (wave & 1) * 32;
    f32x4 acc[2][2];
#pragma unroll
    for (int i = 0; i < 2; ++i)
#pragma unroll
      for (int j = 0; j < 2; ++j) acc[i][j] = f32x4{0.f, 0.f, 0.f, 0.f};
    for (int k0 = 0; k0 < PP; k0 += 32) {
#pragma unroll
      for (int it = 0; it < 2; ++it) {
        const int f = it * 256 + tid;
        const int r = f >> 3, ck = (f & 7) * 4;
        float4 v = *(const float4*)(Wo + (size_t)(m0 + r) * PP + k0 + ck);
        uint2 w;
        w.x = (unsigned)f2bf(v.x) | ((unsigned)f2bf(v.y) << 16);
        w.y = (unsigned)f2bf(v.z) | ((unsigned)f2bf(v.w) << 16);
        *(uint2*)(As + r * 64 + ck * 2) = w;
        v = *(const float4*)(Cm + (size_t)(n0 + r) * PP + k0 + ck);
        w.x = (unsigned)f2bf(v.x) | ((unsigned)f2bf(v.y) << 16);
        w.y = (unsigned)f2bf(v.z) | ((unsigned)f2bf(v.w) << 16);
        *(uint2*)(Bs + r * 64 + ck * 2) = w;
      }
      __syncthreads();
      bf16x8 af[2], bfv[2];
#pragma unroll
      for (int mi = 0; mi < 2; ++mi)
        af[mi] = *(const bf16x8*)(As + (wrow + mi * 16 + l15) * 64 + q * 16);
#pragma unroll
      for (int ni = 0; ni < 2; ++ni)
        bfv[ni] = *(const bf16x8*)(Bs + (wcol + ni * 16 + l15) * 64 + q * 16);
#pragma unroll
      for (int mi = 0; mi < 2; ++mi)
#pragma unroll
        for (int ni = 0; ni < 2; ++ni)
          acc[mi][ni] = __builtin_amdgcn_mfma_f32_16x16x32_bf16(
              af[mi], bfv[ni], acc[mi][ni], 0, 0, 0);
      __syncthreads();
    }
#pragma unroll
    for (int mi = 0; mi < 2; ++mi)
#pragma unroll
      for (int ni = 0; ni < 2; ++ni)
#pragma unroll
        for (int reg = 0; reg < 4; ++reg) {
          const int row = m0 + wrow + mi * 16 + q * 4 + reg;
          const int col = n0 + wcol + ni * 16 + l15;
          CWT_b[(size_t)row * HHH + col] = f2bf(acc[mi][ni][reg]);
        }
  }
}

// ---------------------------------------------------------------------------
// Mega: one block per (batch, 32-row chunk). 1024 blocks, 4/CU co-resident
// (16 waves/CU). Wave w owns cols [w*64, w*64+64) in phases 1-3.
// Phase 1 is barrier-free: whole x chunk staged once (padded stride), Wi
// fragments read directly from L2 (no global_load_lds, no per-K barriers).
// ---------------------------------------------------------------------------
__global__ __launch_bounds__(256, 4) void s4_mega(
    const float* __restrict__ x, const float* __restrict__ a,
    const unsigned short* __restrict__ Wi_b, const float* __restrict__ bi,
    const unsigned short* __restrict__ B_bT,
    const unsigned short* __restrict__ CWT_b, const float* __restrict__ bo,
    float* __restrict__ out, float* __restrict__ carry_g,
    int* __restrict__ flag_g) {
  __shared__ alignas(16) char smem[34304];     // 32*520*2 + 1024 (PL)
  unsigned short* xs = (unsigned short*)smem;  // [32][XTS] x tile bf16
  float* PL = (float*)(smem + 33280);          // 256 f32

  const int tid = threadIdx.x, wave = tid >> 6, lane = tid & 63;
  const int l15 = lane & 15, q = lane >> 4;
  const int bc = blockIdx.x, b = bc >> 7, c = bc & (NCH - 1);
  const size_t row0 = (size_t)bc * LCH;
  const int wc = wave * 64;   // wave column base (phases 1-3)

  // ---- stage x chunk: 32x512 f32 -> bf16 LDS, one barrier total ----
#pragma unroll 4
  for (int it = 0; it < 16; ++it) {
    const int f = it * 256 + tid;
    const int r = f >> 7, c4 = f & 127;
    const float4 v = *(const float4*)(x + (row0 + r) * DIN + c4 * 4);
    uint2 w;
    w.x = (unsigned)f2bf(v.x) | ((unsigned)f2bf(v.y) << 16);
    w.y = (unsigned)f2bf(v.z) | ((unsigned)f2bf(v.w) << 16);
    *(uint2*)(xs + r * XTS + c4 * 4) = w;
  }
  __syncthreads();

  // ---- phase 1: xW = x @ Wi^T (32x256), barrier-free K-loop ----
  f32x4 acc[2][4];
#pragma unroll
  for (int i = 0; i < 2; ++i)
#pragma unroll
    for (int j = 0; j < 4; ++j) acc[i][j] = f32x4{0.f, 0.f, 0.f, 0.f};
#pragma unroll 2
  for (int k0 = 0; k0 < DIN; k0 += 32) {
    bf16x8 af[2], bfv[4];
#pragma unroll
    for (int mi = 0; mi < 2; ++mi)
      af[mi] = *(const bf16x8*)(xs + (mi * 16 + l15) * XTS + k0 + q * 8);
#pragma unroll
    for (int ni = 0; ni < 4; ++ni)
      bfv[ni] = *(const bf16x8*)(Wi_b + (size_t)(wc + ni * 16 + l15) * DIN +
                                 k0 + q * 8);
#pragma unroll
    for (int mi = 0; mi < 2; ++mi)
#pragma unroll
      for (int ni = 0; ni < 4; ++ni)
        acc[mi][ni] = __builtin_amdgcn_mfma_f32_16x16x32_bf16(
            af[mi], bfv[ni], acc[mi][ni], 0, 0, 0);
  }
  __syncthreads();  // xs dead; region reused as xp

  // ---- phase 1.5: relu+bias -> xp [32][XPS] bf16 ----
  unsigned short* xp = (unsigned short*)smem;
#pragma unroll
  for (int ni = 0; ni < 4; ++ni) {
    const int col = wc + ni * 16 + l15;
    const float bb = bi[col];
#pragma unroll
    for (int mi = 0; mi < 2; ++mi)
#pragma unroll
      for (int reg = 0; reg < 4; ++reg) {
        const int row = mi * 16 + q * 4 + reg;
        xp[row * XPS + col] = f2bf(fmaxf(acc[mi][ni][reg] + bb, 0.f));
      }
  }
  __syncthreads();

  // ---- phase 2: u = xp @ B (B^T frags direct from L2) ----
#pragma unroll
  for (int i = 0; i < 2; ++i)
#pragma unroll
    for (int j = 0; j < 4; ++j) acc[i][j] = f32x4{0.f, 0.f, 0.f, 0.f};
  for (int k0 = 0; k0 < PP; k0 += 32) {
    bf16x8 af[2], bfv[4];
#pragma unroll
    for (int mi = 0; mi < 2; ++mi)
      af[mi] = *(const bf16x8*)(xp + (mi * 16 + l15) * XPS + k0 + q * 8);
#pragma unroll
    for (int ni = 0; ni < 4; ++ni)
      bfv[ni] = *(const bf16x8*)(B_bT + (size_t)(wc + ni * 16 + l15) * PP +
                                 k0 + q * 8);
#pragma unroll
    for (int mi = 0; mi < 2; ++mi)
#pragma unroll
      for (int ni = 0; ni < 4; ++ni)
        acc[mi][ni] = __builtin_amdgcn_mfma_f32_16x16x32_bf16(
            af[mi], bfv[ni], acc[mi][ni], 0, 0, 0);
  }

  // ---- phase 3: register scan over 32 rows (zero-init local) ----
  float aC[4], Wz[4];
#pragma unroll
  for (int ni = 0; ni < 4; ++ni) aC[ni] = a[wc + ni * 16 + l15];
#pragma unroll
  for (int ni = 0; ni < 4; ++ni) {
    const float A = aC[ni];
    const float A2 = A * A, A4 = A2 * A2, A8 = A4 * A4, A16 = A8 * A8;
    const float A4q = ((q & 1) ? A4 : 1.f) * ((q & 2) ? A8 : 1.f);
    float W = 0.f;  // state entering current 16-row block (zero-init chain)
#pragma unroll
    for (int mi = 0; mi < 2; ++mi) {
      f32x4 v = acc[mi][ni];
      v.y = fmaf(A, v.x, v.y);
      v.z = fmaf(A, v.y, v.z);
      v.w = fmaf(A, v.z, v.w);
      const float E = v.w;
      const float E0 = __shfl(E, l15, 64);
      const float E1 = __shfl(E, l15 + 16, 64);
      const float E2 = __shfl(E, l15 + 32, 64);
      const float E3 = __shfl(E, l15 + 48, 64);
      const float s1 = E0, s2 = fmaf(A4, s1, E1), s3 = fmaf(A4, s2, E2);
      const float s4 = fmaf(A4, s3, E3);  // 16-row block total
      const float Sq = (q == 0) ? 0.f : (q == 1) ? s1 : (q == 2) ? s2 : s3;
      const float sin_ = fmaf(A4q, W, Sq);  // state entering lane's 4 rows
      v.x = fmaf(A, sin_, v.x);
      v.y = fmaf(A2, sin_, v.y);
      v.z = fmaf(A2 * A, sin_, v.z);
      v.w = fmaf(A4, sin_, v.w);
      acc[mi][ni] = v;
      W = fmaf(A16, W, s4);
    }
    Wz[ni] = W;  // full 32-row zero-init total == chunk carry
  }
  // publish carry, then flag
  if (q == 0) {
#pragma unroll
    for (int ni = 0; ni < 4; ++ni)
      __hip_atomic_store(&carry_g[(size_t)bc * HHH + wc + ni * 16 + l15],
                         Wz[ni], __ATOMIC_RELAXED, __HIP_MEMORY_SCOPE_AGENT);
  }
  __syncthreads();
  if (tid == 0) {
    __threadfence();
    __hip_atomic_store(&flag_g[bc], 1, __ATOMIC_RELEASE,
                       __HIP_MEMORY_SCOPE_AGENT);
  }
  if (tid < c) {
    while (__hip_atomic_load(&flag_g[b * NCH + tid], __ATOMIC_ACQUIRE,
                             __HIP_MEMORY_SCOPE_AGENT) == 0)
      __builtin_amdgcn_s_sleep(8);
  }
  __syncthreads();
  // per-column incoming state P (thread t -> column t), Horner over carries
  {
    const int colp = tid;
    const float A = a[colp];
    float t1 = A;
#pragma unroll
    for (int j = 0; j < 5; ++j) t1 *= t1;  // A^32
    const float A32 = t1, A64 = A32 * A32, A128 = A64 * A64;
    const float* cg = carry_g + (size_t)b * NCH * HHH + colp;
    float P = 0.f;
    int j = 0;
    for (; j + 4 <= c; j += 4) {
      const float c0 = ld_carry(cg + (size_t)j * HHH);
      const float c1 = ld_carry(cg + (size_t)(j + 1) * HHH);
      const float c2 = ld_carry(cg + (size_t)(j + 2) * HHH);
      const float c3 = ld_carry(cg + (size_t)(j + 3) * HHH);
      P = fmaf(A128, P, fmaf(A32, fmaf(A32, fmaf(A32, c0, c1), c2), c3));
    }
    for (; j < c; ++j) P = fmaf(A32, P, ld_carry(cg + (size_t)j * HHH));
    PL[colp] = P;
  }
  __syncthreads();
  // fixup: h_row += A^(row+1) * P,  row = 16*mi + 4*q + reg
#pragma unroll
  for (int ni = 0; ni < 4; ++ni) {
    const float A = aC[ni];
    const float A2 = A * A, A4 = A2 * A2, A8 = A4 * A4, A16 = A8 * A8;
    const float A4q = ((q & 1) ? A4 : 1.f) * ((q & 2) ? A8 : 1.f);
    const float P = PL[wc + ni * 16 + l15];
    float fm = A4q * A * P;  // A^(4q+1) * P
#pragma unroll
    for (int mi = 0; mi < 2; ++mi) {
      f32x4 v = acc[mi][ni];
      v.x += fm;
      v.y = fmaf(A, fm, v.y);
      v.z = fmaf(A2, fm, v.z);
      v.w = fmaf(A2 * A, fm, v.w);
      acc[mi][ni] = v;
      fm *= A16;
    }
  }
  __syncthreads();  // PL consumed; xp region about to be overwritten

  // ---- phase 4: out = hs @ CWT^T + bo ----
  unsigned short* hsL = (unsigned short*)smem;  // [32][XPS] bf16
#pragma unroll
  for (int ni = 0; ni < 4; ++ni) {
    const int col = wc + ni * 16 + l15;
#pragma unroll
    for (int mi = 0; mi < 2; ++mi)
#pragma unroll
      for (int reg = 0; reg < 4; ++reg)
        hsL[(mi * 16 + q * 4 + reg) * XPS + col] = f2bf(acc[mi][ni][reg]);
  }
  __syncthreads();

#pragma unroll
  for (int g = 0; g < 2; ++g) {
    const int gc0 = wave * 128 + g * 64;
    f32x4 oacc[2][4];
#pragma unroll
    for (int i = 0; i < 2; ++i)
#pragma unroll
      for (int j = 0; j < 4; ++j) oacc[i][j] = f32x4{0.f, 0.f, 0.f, 0.f};
    for (int k0 = 0; k0 < HHH; k0 += 32) {
      bf16x8 af[2], bfv[4];
#pragma unroll
      for (int mi = 0; mi < 2; ++mi)
        af[mi] = *(const bf16x8*)(hsL + (mi * 16 + l15) * XPS + k0 + q * 8);
#pragma unroll
      for (int ni = 0; ni < 4; ++ni)
        bfv[ni] = *(const bf16x8*)(CWT_b +
                                   (size_t)(gc0 + ni * 16 + l15) * HHH + k0 +
                                   q * 8);
#pragma unroll
      for (int mi = 0; mi < 2; ++mi)
#pragma unroll
        for (int ni = 0; ni < 4; ++ni)
          oacc[mi][ni] = __builtin_amdgcn_mfma_f32_16x16x32_bf16(
              af[mi], bfv[ni], oacc[mi][ni], 0, 0, 0);
    }
#pragma unroll
    for (int ni = 0; ni < 4; ++ni) {
      const int ocol = gc0 + ni * 16 + l15;
      const float bb = bo[ocol];
#pragma unroll
      for (int mi = 0; mi < 2; ++mi)
#pragma unroll
        for (int reg = 0; reg < 4; ++reg) {
          const int row = mi * 16 + q * 4 + reg;
          out[(row0 + row) * DOUT + ocol] = oacc[mi][ni][reg] + bb;
        }
    }
  }
}

// ---------------------------------------------------------------------------
extern "C" void kernel_launch(void* const* d_in, const int* in_sizes, int n_in,
                              void* d_out, int out_size, void* d_ws,
                              size_t ws_size, hipStream_t stream) {
  const float* x  = (const float*)d_in[0];
  const float* a  = (const float*)d_in[1];
  const float* Bm = (const float*)d_in[2];
  const float* Cm = (const float*)d_in[3];
  const float* Wi = (const float*)d_in[4];
  const float* bi = (const float*)d_in[5];
  const float* Wo = (const float*)d_in[6];
  const float* bo = (const float*)d_in[7];
  float* out = (float*)d_out;

  char* ws = (char*)d_ws;
  unsigned short* Wi_b  = (unsigned short*)ws; ws += (size_t)PP * DIN * 2;
  unsigned short* B_bT  = (unsigned short*)ws; ws += (size_t)HHH * PP * 2;
  unsigned short* CWT_b = (unsigned short*)ws; ws += (size_t)DOUT * HHH * 2;
  float* carry_g = (float*)ws; ws += (size_t)NBLK * HHH * 4;
  int* flag_g = (int*)ws;

  prep_k<<<177, 256, 0, stream>>>(Wi, Wo, Cm, Bm, Wi_b, B_bT, CWT_b, flag_g);
  s4_mega<<<NBLK, 256, 0, stream>>>(x, a, Wi_b, bi, B_bT, CWT_b, bo, out,
                                    carry_g, flag_g);
}

// Round 2
// 188.731 us; speedup vs baseline: 1.7308x; 1.7308x over previous
//
#include <hip/hip_runtime.h>

#define BSZN 8
#define TT 4096
#define DIN 512
#define PP 256
#define HHH 256
#define DOUT 512
#define LCH 64              // scan chunk length == row tile
#define NCH (TT / LCH)      // 64 chunks per batch
#define NBLK (BSZN * NCH)   // 512 blocks -> 2/CU co-resident
#define XPS 264             // xp/hsL row stride (bf16 elems), 528 B
#define AST 136             // As row stride (bytes), 64 bf16 + 8 B pad

typedef __attribute__((ext_vector_type(8))) short bf16x8;
typedef __attribute__((ext_vector_type(4))) float f32x4;

#define GLOBAL_AS __attribute__((address_space(1)))
#define LDS_AS __attribute__((address_space(3)))

static __device__ __forceinline__ void gld_lds16(const void* g, void* l) {
  __builtin_amdgcn_global_load_lds((const GLOBAL_AS unsigned int*)g,
                                   (LDS_AS unsigned int*)l, 16, 0, 0);
}

static __device__ __forceinline__ unsigned short f2bf(float x) {
  union { float f; unsigned u; } t{x};
  unsigned r = t.u + 0x7fffu + ((t.u >> 16) & 1u);  // RNE
  return (unsigned short)(r >> 16);
}

static __device__ __forceinline__ float ld_carry(const float* p) {
  return __hip_atomic_load(p, __ATOMIC_RELAXED, __HIP_MEMORY_SCOPE_AGENT);
}

// Tiled-rotated weight layouts: K-major tiles of 32 k-elems (64 B rows),
// 16 B slot rotated by (row>>1) so LDS ds_read_b128 frags are conflict-free
// while global_load_lds staging stays perfectly linear.
// pos(elems) = tile*(NROWS*32) + row*32 + (((k>>3)&3 + (row>>1))&3)*8 + (k&7)

// ---------------------------------------------------------------------------
// Prep: Wi->Wi_t (128 blk), B->B_t transposed-tiled (16 blk), flags (1 blk),
// CWT = Wo @ C^T -> CWT_t via 32 blocks of 64x64 tiles. Grid = 177.
// ---------------------------------------------------------------------------
__global__ __launch_bounds__(256) void prep_k(
    const float* __restrict__ Wi, const float* __restrict__ Wo,
    const float* __restrict__ Cm, const float* __restrict__ Bm,
    unsigned short* __restrict__ Wi_t, unsigned short* __restrict__ B_t,
    unsigned short* __restrict__ CWT_t, int* __restrict__ flag_g) {
  __shared__ alignas(16) char smem[8192];
  const int b = blockIdx.x, tid = threadIdx.x;
  if (b < 128) {                       // Wi convert+tile (256x512)
    const int idx = b * 1024 + tid * 4;
    const int row = idx >> 9, d = idx & 511;
    const float4 v = *(const float4*)(Wi + idx);
    uint2 w;
    w.x = (unsigned)f2bf(v.x) | ((unsigned)f2bf(v.y) << 16);
    w.y = (unsigned)f2bf(v.z) | ((unsigned)f2bf(v.w) << 16);
    const int tile = d >> 5, kc = (d >> 3) & 3, s = (kc + (row >> 1)) & 3;
    *(uint2*)(Wi_t + tile * 8192 + row * 32 + s * 8 + (d & 7)) = w;
  } else if (b < 144) {                // B transpose+tile: 16 tiles of 64x64
    const int t = b - 128;
    const int p0 = (t >> 2) * 64, h0 = (t & 3) * 64;
#pragma unroll 4
    for (int it = 0; it < 16; ++it) {
      const int f = it * 256 + tid;
      const int h = h0 + (f >> 6), p = p0 + (f & 63);
      const unsigned short val = f2bf(Bm[(size_t)p * HHH + h]);
      const int tile = p >> 5, kc = (p >> 3) & 3, s = (kc + (h >> 1)) & 3;
      B_t[tile * 8192 + h * 32 + s * 8 + (p & 7)] = val;
    }
  } else if (b == 144) {               // zero lookback flags (ws poisoned!)
    flag_g[tid] = 0;
    flag_g[tid + 256] = 0;
  } else {                             // CWT: 32 blocks of 64x64 tiles
    const int t = b - 145;
    const int m0 = (t >> 2) * 64, n0 = (t & 3) * 64;
    char* As = smem;
    char* Bs = smem + 4096;
    const int wave = tid >> 6, lane = tid & 63;
    const int l15 = lane & 15, q = lane >> 4;
    const int wrow = (wave >> 1) * 32, wcol = (wave & 1) * 32;
    f32x4 acc[2][2];
#pragma unroll
    for (int i = 0; i < 2; ++i)
#pragma unroll
      for (int j = 0; j < 2; ++j) acc[i][j] = f32x4{0.f, 0.f, 0.f, 0.f};
    for (int k0 = 0; k0 < PP; k0 += 32) {
#pragma unroll
      for (int it = 0; it < 2; ++it) {
        const int f = it * 256 + tid;
        const int r = f >> 3, ck = (f & 7) * 4;
        float4 v = *(const float4*)(Wo + (size_t)(m0 + r) * PP + k0 + ck);
        uint2 w;
        w.x = (unsigned)f2bf(v.x) | ((unsigned)f2bf(v.y) << 16);
        w.y = (unsigned)f2bf(v.z) | ((unsigned)f2bf(v.w) << 16);
        *(uint2*)(As + r * 64 + ck * 2) = w;
        v = *(const float4*)(Cm + (size_t)(n0 + r) * PP + k0 + ck);
        w.x = (unsigned)f2bf(v.x) | ((unsigned)f2bf(v.y) << 16);
        w.y = (unsigned)f2bf(v.z) | ((unsigned)f2bf(v.w) << 16);
        *(uint2*)(Bs + r * 64 + ck * 2) = w;
      }
      __syncthreads();
      bf16x8 af[2], bfv[2];
#pragma unroll
      for (int mi = 0; mi < 2; ++mi)
        af[mi] = *(const bf16x8*)(As + (wrow + mi * 16 + l15) * 64 + q * 16);
#pragma unroll
      for (int ni = 0; ni < 2; ++ni)
        bfv[ni] = *(const bf16x8*)(Bs + (wcol + ni * 16 + l15) * 64 + q * 16);
#pragma unroll
      for (int mi = 0; mi < 2; ++mi)
#pragma unroll
        for (int ni = 0; ni < 2; ++ni)
          acc[mi][ni] = __builtin_amdgcn_mfma_f32_16x16x32_bf16(
              af[mi], bfv[ni], acc[mi][ni], 0, 0, 0);
      __syncthreads();
    }
#pragma unroll
    for (int mi = 0; mi < 2; ++mi)
#pragma unroll
      for (int ni = 0; ni < 2; ++ni)
#pragma unroll
        for (int reg = 0; reg < 4; ++reg) {
          const int row = m0 + wrow + mi * 16 + q * 4 + reg;  // o dim
          const int col = n0 + wcol + ni * 16 + l15;          // h dim (K)
          const int tile = col >> 5, kc = (col >> 3) & 3;
          const int s = (kc + (row >> 1)) & 3;
          CWT_t[tile * 16384 + row * 32 + s * 8 + (col & 7)] =
              f2bf(acc[mi][ni][reg]);
        }
  }
}

// ---------------------------------------------------------------------------
// Mega: one block per (batch, 64-row chunk). 512 blocks, 2/CU co-resident.
// ALL weight fragments staged to LDS via linear global_load_lds bursts from
// pre-tiled rotated layouts; zero scattered per-lane L2 fragment reads.
// ---------------------------------------------------------------------------
__global__ __launch_bounds__(256, 2) void s4_mega(
    const float* __restrict__ x, const float* __restrict__ a,
    const unsigned short* __restrict__ Wi_t, const float* __restrict__ bi,
    const unsigned short* __restrict__ B_t,
    const unsigned short* __restrict__ CWT_t, const float* __restrict__ bo,
    float* __restrict__ out, float* __restrict__ carry_g,
    int* __restrict__ flag_g) {
  __shared__ alignas(16) char smem[67584];
  char* As = smem;                       // phase1 x tile [64][AST] (8704 B)
  unsigned short* xp = (unsigned short*)smem;  // [64][XPS] bf16 (33792 B)
  char* TB0 = smem + 33792;              // staging tile 0 (16 KB)
  char* TB1 = smem + 50176;              // staging tile 1 (16 KB)
  float* PL = (float*)(smem + 66560);    // 256 f32

  const int tid = threadIdx.x, wave = tid >> 6, lane = tid & 63;
  const int l15 = lane & 15, q = lane >> 4;
  const int bc = blockIdx.x, b = bc >> 6, c = bc & (NCH - 1);
  const size_t row0 = (size_t)bc * LCH;
  const int wc = wave * 64;   // wave column base (phases 1-3)

  // precomputed fragment offsets
  int wrot[4];                // 256-row K32 tile rows for Wi/B frags (bytes)
#pragma unroll
  for (int ni = 0; ni < 4; ++ni) {
    const int r = wc + ni * 16 + l15;
    wrot[ni] = r * 64 + (((q + (r >> 1)) & 3) << 4);
  }
  int afb[4];                 // As read offsets (bytes)
#pragma unroll
  for (int mi = 0; mi < 4; ++mi) afb[mi] = (mi * 16 + l15) * AST + q * 16;
  int xpb[4];                 // xp/hsL read offsets (elems)
#pragma unroll
  for (int mi = 0; mi < 4; ++mi) xpb[mi] = (mi * 16 + l15) * XPS + q * 8;

  // ================= phase 1: xW = x @ Wi^T (64x256) =================
  f32x4 acc[4][4];
#pragma unroll
  for (int i = 0; i < 4; ++i)
#pragma unroll
    for (int j = 0; j < 4; ++j) acc[i][j] = f32x4{0.f, 0.f, 0.f, 0.f};

  float4 xv[4];
#pragma unroll
  for (int i = 0; i < 4; ++i) {
    const int f = i * 256 + tid;
    xv[i] = *(const float4*)(x + (row0 + (f >> 4)) * DIN + (f & 15) * 4);
  }
  for (int t = 0; t < 8; ++t) {  // K-step = 64 (two 32-k tiles per step)
    {  // write prefetched x slab into As
#pragma unroll
      for (int i = 0; i < 4; ++i) {
        const int f = i * 256 + tid;
        uint2 w;
        w.x = (unsigned)f2bf(xv[i].x) | ((unsigned)f2bf(xv[i].y) << 16);
        w.y = (unsigned)f2bf(xv[i].z) | ((unsigned)f2bf(xv[i].w) << 16);
        *(uint2*)(As + (f >> 4) * AST + (f & 15) * 8) = w;
      }
    }
    {  // stage Wi tiles 2t, 2t+1 -> TB0, TB1 (linear 1 KB bursts)
      const char* gw = (const char*)Wi_t + t * 32768 + wave * 4096 + lane * 16;
      char* l0 = TB0 + wave * 4096 + lane * 16;
      char* l1 = TB1 + wave * 4096 + lane * 16;
#pragma unroll
      for (int i = 0; i < 4; ++i) {
        gld_lds16(gw + i * 1024, l0 + i * 1024);
        gld_lds16(gw + 16384 + i * 1024, l1 + i * 1024);
      }
    }
    __syncthreads();
    if (t < 7) {  // prefetch next x slab
#pragma unroll
      for (int i = 0; i < 4; ++i) {
        const int f = i * 256 + tid;
        xv[i] = *(const float4*)(x + (row0 + (f >> 4)) * DIN + (t + 1) * 64 +
                                 (f & 15) * 4);
      }
    }
    bf16x8 af[4][2], bfv[4][2];
#pragma unroll
    for (int mi = 0; mi < 4; ++mi) {
      af[mi][0] = *(const bf16x8*)(As + afb[mi]);
      af[mi][1] = *(const bf16x8*)(As + afb[mi] + 64);
    }
#pragma unroll
    for (int ni = 0; ni < 4; ++ni) {
      bfv[ni][0] = *(const bf16x8*)(TB0 + wrot[ni]);
      bfv[ni][1] = *(const bf16x8*)(TB1 + wrot[ni]);
    }
#pragma unroll
    for (int kk = 0; kk < 2; ++kk)
#pragma unroll
      for (int mi = 0; mi < 4; ++mi)
#pragma unroll
        for (int ni = 0; ni < 4; ++ni)
          acc[mi][ni] = __builtin_amdgcn_mfma_f32_16x16x32_bf16(
              af[mi][kk], bfv[ni][kk], acc[mi][ni], 0, 0, 0);
    __syncthreads();
  }

  // ============ phase 1.5: relu+bias -> xp [64][XPS] bf16 ============
#pragma unroll
  for (int ni = 0; ni < 4; ++ni) {
    const int col = wc + ni * 16 + l15;
    const float bb = bi[col];
#pragma unroll
    for (int mi = 0; mi < 4; ++mi)
#pragma unroll
      for (int reg = 0; reg < 4; ++reg) {
        const int row = mi * 16 + q * 4 + reg;
        xp[row * XPS + col] = f2bf(fmaxf(acc[mi][ni][reg] + bb, 0.f));
      }
  }
  __syncthreads();

  // ============ phase 2: u = xp @ B (B tiles staged) ============
#pragma unroll
  for (int i = 0; i < 4; ++i)
#pragma unroll
    for (int j = 0; j < 4; ++j) acc[i][j] = f32x4{0.f, 0.f, 0.f, 0.f};
  for (int t = 0; t < 4; ++t) {  // K-step = 64
    {
      const char* gw = (const char*)B_t + t * 32768 + wave * 4096 + lane * 16;
      char* l0 = TB0 + wave * 4096 + lane * 16;
      char* l1 = TB1 + wave * 4096 + lane * 16;
#pragma unroll
      for (int i = 0; i < 4; ++i) {
        gld_lds16(gw + i * 1024, l0 + i * 1024);
        gld_lds16(gw + 16384 + i * 1024, l1 + i * 1024);
      }
    }
    __syncthreads();
    bf16x8 af[4][2], bfv[4][2];
#pragma unroll
    for (int mi = 0; mi < 4; ++mi) {
      af[mi][0] = *(const bf16x8*)(xp + xpb[mi] + t * 64);
      af[mi][1] = *(const bf16x8*)(xp + xpb[mi] + t * 64 + 32);
    }
#pragma unroll
    for (int ni = 0; ni < 4; ++ni) {
      bfv[ni][0] = *(const bf16x8*)(TB0 + wrot[ni]);
      bfv[ni][1] = *(const bf16x8*)(TB1 + wrot[ni]);
    }
#pragma unroll
    for (int kk = 0; kk < 2; ++kk)
#pragma unroll
      for (int mi = 0; mi < 4; ++mi)
#pragma unroll
        for (int ni = 0; ni < 4; ++ni)
          acc[mi][ni] = __builtin_amdgcn_mfma_f32_16x16x32_bf16(
              af[mi][kk], bfv[ni][kk], acc[mi][ni], 0, 0, 0);
    __syncthreads();
  }

  // ============ phase 3: register scan (zero-init local) ============
  float aC[4], Wz[4];
#pragma unroll
  for (int ni = 0; ni < 4; ++ni) aC[ni] = a[wc + ni * 16 + l15];
#pragma unroll
  for (int ni = 0; ni < 4; ++ni) {
    const float A = aC[ni];
    const float A2 = A * A, A4 = A2 * A2, A8 = A4 * A4, A16 = A8 * A8;
    const float A4q = ((q & 1) ? A4 : 1.f) * ((q & 2) ? A8 : 1.f);
    float W = 0.f;  // state entering current 16-row block (zero-init chain)
#pragma unroll
    for (int mi = 0; mi < 4; ++mi) {
      f32x4 v = acc[mi][ni];
      v.y = fmaf(A, v.x, v.y);
      v.z = fmaf(A, v.y, v.z);
      v.w = fmaf(A, v.z, v.w);
      const float E = v.w;
      const float E0 = __shfl(E, l15, 64);
      const float E1 = __shfl(E, l15 + 16, 64);
      const float E2 = __shfl(E, l15 + 32, 64);
      const float E3 = __shfl(E, l15 + 48, 64);
      const float s1 = E0, s2 = fmaf(A4, s1, E1), s3 = fmaf(A4, s2, E2);
      const float s4 = fmaf(A4, s3, E3);  // 16-row block total
      const float Sq = (q == 0) ? 0.f : (q == 1) ? s1 : (q == 2) ? s2 : s3;
      const float sin_ = fmaf(A4q, W, Sq);  // state entering lane's 4 rows
      v.x = fmaf(A, sin_, v.x);
      v.y = fmaf(A2, sin_, v.y);
      v.z = fmaf(A2 * A, sin_, v.z);
      v.w = fmaf(A4, sin_, v.w);
      acc[mi][ni] = v;
      W = fmaf(A16, W, s4);
    }
    Wz[ni] = W;  // full 64-row zero-init total == chunk carry
  }
  // publish carry, then flag
  if (q == 0) {
#pragma unroll
    for (int ni = 0; ni < 4; ++ni)
      __hip_atomic_store(&carry_g[(size_t)bc * HHH + wc + ni * 16 + l15],
                         Wz[ni], __ATOMIC_RELAXED, __HIP_MEMORY_SCOPE_AGENT);
  }
  __syncthreads();
  if (tid == 0) {
    __threadfence();
    __hip_atomic_store(&flag_g[bc], 1, __ATOMIC_RELEASE,
                       __HIP_MEMORY_SCOPE_AGENT);
  }
  if (tid < c) {
    while (__hip_atomic_load(&flag_g[b * NCH + tid], __ATOMIC_ACQUIRE,
                             __HIP_MEMORY_SCOPE_AGENT) == 0)
      __builtin_amdgcn_s_sleep(8);
  }
  __syncthreads();
  // per-column incoming state P (thread t -> column t), Horner over carries
  {
    const int colp = tid;
    const float A = a[colp];
    float t1 = A;
#pragma unroll
    for (int j = 0; j < 6; ++j) t1 *= t1;  // A^64
    const float A64 = t1, A128 = A64 * A64, A256 = A128 * A128;
    const float* cg = carry_g + (size_t)b * NCH * HHH + colp;
    float P = 0.f;
    int j = 0;
    for (; j + 4 <= c; j += 4) {
      const float c0 = ld_carry(cg + (size_t)j * HHH);
      const float c1 = ld_carry(cg + (size_t)(j + 1) * HHH);
      const float c2 = ld_carry(cg + (size_t)(j + 2) * HHH);
      const float c3 = ld_carry(cg + (size_t)(j + 3) * HHH);
      P = fmaf(A256, P, fmaf(A64, fmaf(A64, fmaf(A64, c0, c1), c2), c3));
    }
    for (; j < c; ++j) P = fmaf(A64, P, ld_carry(cg + (size_t)j * HHH));
    PL[colp] = P;
  }
  __syncthreads();
  // fixup: h_row += A^(row+1) * P,  row = 16*mi + 4*q + reg
#pragma unroll
  for (int ni = 0; ni < 4; ++ni) {
    const float A = aC[ni];
    const float A2 = A * A, A4 = A2 * A2, A8 = A4 * A4, A16 = A8 * A8;
    const float A4q = ((q & 1) ? A4 : 1.f) * ((q & 2) ? A8 : 1.f);
    const float P = PL[wc + ni * 16 + l15];
    float fm = A4q * A * P;  // A^(4q+1) * P
#pragma unroll
    for (int mi = 0; mi < 4; ++mi) {
      f32x4 v = acc[mi][ni];
      v.x += fm;
      v.y = fmaf(A, fm, v.y);
      v.z = fmaf(A2, fm, v.z);
      v.w = fmaf(A2 * A, fm, v.w);
      acc[mi][ni] = v;
      fm *= A16;
    }
  }
  __syncthreads();  // PL consumed; xp region about to be overwritten

  // ============ phase 4: out = hs @ CWT^T + bo ============
  unsigned short* hsL = (unsigned short*)smem;  // [64][XPS] bf16
#pragma unroll
  for (int ni = 0; ni < 4; ++ni) {
    const int col = wc + ni * 16 + l15;
#pragma unroll
    for (int mi = 0; mi < 4; ++mi)
#pragma unroll
      for (int reg = 0; reg < 4; ++reg)
        hsL[(mi * 16 + q * 4 + reg) * XPS + col] = f2bf(acc[mi][ni][reg]);
  }
  __syncthreads();

  int crot[2][4];  // 512-row K32 CWT tile offsets (bytes)
#pragma unroll
  for (int g = 0; g < 2; ++g)
#pragma unroll
    for (int ni = 0; ni < 4; ++ni) {
      const int r = wave * 128 + g * 64 + ni * 16 + l15;
      crot[g][ni] = r * 64 + (((q + (r >> 1)) & 3) << 4);
    }

  f32x4 oacc[2][4][4];  // both 64-col groups live: stage each tile once
#pragma unroll
  for (int g = 0; g < 2; ++g)
#pragma unroll
    for (int i = 0; i < 4; ++i)
#pragma unroll
      for (int j = 0; j < 4; ++j) oacc[g][i][j] = f32x4{0.f, 0.f, 0.f, 0.f};
  for (int t = 0; t < 8; ++t) {  // K-step = 32, tile [512][32] = 32 KB
    {
      const char* gw =
          (const char*)CWT_t + t * 32768 + wave * 8192 + lane * 16;
      char* l0 = TB0 + wave * 8192 + lane * 16;
#pragma unroll
      for (int i = 0; i < 8; ++i) gld_lds16(gw + i * 1024, l0 + i * 1024);
    }
    __syncthreads();
    bf16x8 af[4], bfv[2][4];
#pragma unroll
    for (int mi = 0; mi < 4; ++mi)
      af[mi] = *(const bf16x8*)(hsL + xpb[mi] + t * 32);
#pragma unroll
    for (int g = 0; g < 2; ++g)
#pragma unroll
      for (int ni = 0; ni < 4; ++ni)
        bfv[g][ni] = *(const bf16x8*)(TB0 + crot[g][ni]);
#pragma unroll
    for (int g = 0; g < 2; ++g)
#pragma unroll
      for (int mi = 0; mi < 4; ++mi)
#pragma unroll
        for (int ni = 0; ni < 4; ++ni)
          oacc[g][mi][ni] = __builtin_amdgcn_mfma_f32_16x16x32_bf16(
              af[mi], bfv[g][ni], oacc[g][mi][ni], 0, 0, 0);
    __syncthreads();
  }
#pragma unroll
  for (int g = 0; g < 2; ++g)
#pragma unroll
    for (int ni = 0; ni < 4; ++ni) {
      const int ocol = wave * 128 + g * 64 + ni * 16 + l15;
      const float bb = bo[ocol];
#pragma unroll
      for (int mi = 0; mi < 4; ++mi)
#pragma unroll
        for (int reg = 0; reg < 4; ++reg) {
          const int row = mi * 16 + q * 4 + reg;
          out[(row0 + row) * DOUT + ocol] = oacc[g][mi][ni][reg] + bb;
        }
    }
}

// ---------------------------------------------------------------------------
extern "C" void kernel_launch(void* const* d_in, const int* in_sizes, int n_in,
                              void* d_out, int out_size, void* d_ws,
                              size_t ws_size, hipStream_t stream) {
  const float* x  = (const float*)d_in[0];
  const float* a  = (const float*)d_in[1];
  const float* Bm = (const float*)d_in[2];
  const float* Cm = (const float*)d_in[3];
  const float* Wi = (const float*)d_in[4];
  const float* bi = (const float*)d_in[5];
  const float* Wo = (const float*)d_in[6];
  const float* bo = (const float*)d_in[7];
  float* out = (float*)d_out;

  char* ws = (char*)d_ws;
  unsigned short* Wi_t  = (unsigned short*)ws; ws += (size_t)PP * DIN * 2;
  unsigned short* B_t   = (unsigned short*)ws; ws += (size_t)HHH * PP * 2;
  unsigned short* CWT_t = (unsigned short*)ws; ws += (size_t)DOUT * HHH * 2;
  float* carry_g = (float*)ws; ws += (size_t)NBLK * HHH * 4;
  int* flag_g = (int*)ws;

  prep_k<<<177, 256, 0, stream>>>(Wi, Wo, Cm, Bm, Wi_t, B_t, CWT_t, flag_g);
  s4_mega<<<NBLK, 256, 0, stream>>>(x, a, Wi_t, bi, B_t, CWT_t, bo, out,
                                    carry_g, flag_g);
}